// Round 4
// baseline (381.575 us; speedup 1.0000x reference)
//
#include <hip/hip_runtime.h>
#include <cstdint>

#pragma clang fp contract(off)

#define BB 64
#define PP 32768
#define OO 50
#define THRESH_F 0.5f
#define VAR0 0.1f
#define VAR1 0.2f
#define NEGPOS_I 3
#define SS 32            // k_loss splits per batch
#define T1 8             // priors per thread in k_match
#define NB0 2048         // pass-0 bins (bits 30:20, sign always 0)

typedef unsigned long long u64;

// ---- K0: zero the atomically-accumulated region (hist0 + bpm + ccnt) ----
__global__ void k_zero(float4* __restrict__ dst, int n4) {
    int i = blockIdx.x * blockDim.x + threadIdx.x;
    if (i < n4) dst[i] = make_float4(0.f, 0.f, 0.f, 0.f);
}

// ---- K1: fused matcher. Row-best per prior (regs) + column-best per truth
// (wave u64 max-reduce -> one global atomicMax per wave per truth).
// Packing (iou_bits<<32)|(PP-p): max == max IoU, smallest p on ties.
// Division replaced by v_rcp_f32: ordering differs from IEEE div only in
// ~ulp near-ties; impact O(1e-3) on outputs vs 0.138 threshold.
__global__ void __launch_bounds__(256)
k_match(const float* __restrict__ priors, const float* __restrict__ targets,
        float* __restrict__ bto, int* __restrict__ bti, u64* __restrict__ bpm) {
    __shared__ float tr4[OO * 4];
    __shared__ float trA[OO];
    int b = blockIdx.y, tid = threadIdx.x;
    for (int i = tid; i < OO * 4; i += 256)
        tr4[i] = targets[(size_t)(b * OO + (i >> 2)) * 5 + (i & 3)];
    __syncthreads();
    if (tid < OO)
        trA[tid] = (tr4[tid*4+2] - tr4[tid*4]) * (tr4[tid*4+3] - tr4[tid*4+1]);
    __syncthreads();

    int p0 = blockIdx.x * (256 * T1) + tid * T1;
    float bx0[T1], by0[T1], bx1[T1], by1[T1], aB[T1];
    for (int j = 0; j < T1; ++j) {
        float4 pr = ((const float4*)priors)[p0 + j];
        bx0[j] = pr.x - pr.z * 0.5f; by0[j] = pr.y - pr.w * 0.5f;
        bx1[j] = pr.x + pr.z * 0.5f; by1[j] = pr.y + pr.w * 0.5f;
        aB[j] = (bx1[j] - bx0[j]) * (by1[j] - by0[j]);
    }
    float rbv[T1]; int rbi[T1];
    for (int j = 0; j < T1; ++j) { rbv[j] = -1.0f; rbi[j] = 0; }

    for (int t = 0; t < OO; ++t) {
        float t0 = tr4[t*4], t1v = tr4[t*4+1], t2 = tr4[t*4+2], t3 = tr4[t*4+3];
        float aA = trA[t];
        float cbv = -1.0f; int cbp = 0;
        for (int j = 0; j < T1; ++j) {
            float ltx = fmaxf(t0, bx0[j]), lty = fmaxf(t1v, by0[j]);
            float rbx = fminf(t2, bx1[j]), rby = fminf(t3, by1[j]);
            float wx = fmaxf(rbx - ltx, 0.f), wy = fmaxf(rby - lty, 0.f);
            float inter = wx * wy;
            float uni = aA + aB[j] - inter;
            float v = inter * __builtin_amdgcn_rcpf(uni);
            if (v > rbv[j]) { rbv[j] = v; rbi[j] = t; }   // row: first-max
            if (v > cbv) { cbv = v; cbp = p0 + j; }       // col: smallest p
        }
        u64 pk = ((u64)__float_as_uint(cbv) << 32) | (unsigned)(PP - cbp);
        for (int s = 32; s >= 1; s >>= 1) {
            u64 o = __shfl_xor(pk, s, 64);
            if (o > pk) pk = o;
        }
        if ((tid & 63) == 0) atomicMax(&bpm[b * OO + t], pk);
    }
    size_t bp = (size_t)b * PP + p0;
    ((float4*)bto)[bp >> 2]       = make_float4(rbv[0], rbv[1], rbv[2], rbv[3]);
    ((float4*)bto)[(bp >> 2) + 1] = make_float4(rbv[4], rbv[5], rbv[6], rbv[7]);
    ((int4*)bti)[bp >> 2]         = make_int4(rbi[0], rbi[1], rbi[2], rbi[3]);
    ((int4*)bti)[(bp >> 2) + 1]   = make_int4(rbi[4], rbi[5], rbi[6], rbi[7]);
}

// ---- K2: forced match — sequential per batch, last write wins ----
__global__ void k_force(const u64* __restrict__ bpm,
                        float* __restrict__ bto, int* __restrict__ bti) {
    __shared__ int pidx[OO];
    int b = blockIdx.x, tid = threadIdx.x;
    if (tid < OO) pidx[tid] = PP - (int)(unsigned)(bpm[b * OO + tid] & 0xFFFFFFFFull);
    __syncthreads();
    if (tid == 0) {
        for (int j = 0; j < OO; ++j) {
            int p = pidx[j];
            bto[(size_t)b * PP + p] = 2.0f;
            bti[(size_t)b * PP + p] = j;
        }
    }
}

// ---- K3: conf/encode/smooth-L1/lc; writes lcm + partials + pass-0 hist ----
__global__ void __launch_bounds__(256)
k_loss(const float* __restrict__ arm_loc, const float* __restrict__ arm_conf,
       const float* __restrict__ priors, const float* __restrict__ targets,
       const float* __restrict__ bto, const int* __restrict__ bti,
       float* __restrict__ lcm, float* __restrict__ pll,
       float* __restrict__ pplc, int* __restrict__ pnp,
       int* __restrict__ Hc0, float* __restrict__ Hs0) {
    __shared__ int hc[NB0]; __shared__ float hs[NB0];
    __shared__ float s1[256], s2[256]; __shared__ int s3[256];
    int b = blockIdx.y, s = blockIdx.x, tid = threadIdx.x;
    for (int i = tid; i < NB0; i += 256) { hc[i] = 0; hs[i] = 0.f; }
    __syncthreads();

    int p = s * 1024 + tid * 4;
    size_t bp = (size_t)b * PP + p;
    float4 ov4 = ((const float4*)bto)[bp >> 2];
    int4   ti4 = ((const int4*)bti)[bp >> 2];
    float4 ca  = ((const float4*)arm_conf)[bp >> 1];
    float4 cb  = ((const float4*)arm_conf)[(bp >> 1) + 1];
    float ovs[4] = {ov4.x, ov4.y, ov4.z, ov4.w};
    int   tis[4] = {ti4.x, ti4.y, ti4.z, ti4.w};
    float cs[8]  = {ca.x, ca.y, ca.z, ca.w, cb.x, cb.y, cb.z, cb.w};

    float ll = 0.0f, plc = 0.0f; int np = 0;
    float outv[4];
    for (int c = 0; c < 4; ++c) {
        int ti = tis[c];
        const float* tb = &targets[(size_t)(b * OO + ti) * 5];
        int label = (tb[4] >= 0.0f) ? 1 : 0;
        int conf = (ovs[c] < THRESH_F) ? 0 : label;
        float c0 = cs[c * 2], c1 = cs[c * 2 + 1];
        float m = fmaxf(c0, c1);
        // identical to log(exp(c0-m)+exp(c1-m))+m: max term is expf(0)==1
        float lse = __logf(1.0f + __expf(-fabsf(c0 - c1))) + m;
        float picked = (conf == 1) ? c1 : c0;
        float lc = lse - picked;
        bool pos = conf > 0;
        outv[c] = pos ? 0.0f : lc;
        if (pos) {
            np++; plc += lc;
            float4 pr = ((const float4*)priors)[p + c];
            float gx = ((tb[0] + tb[2]) * 0.5f - pr.x) / (VAR0 * pr.z);
            float gy = ((tb[1] + tb[3]) * 0.5f - pr.y) / (VAR0 * pr.w);
            float gw = __logf((tb[2] - tb[0]) / pr.z) / VAR1;
            float gh = __logf((tb[3] - tb[1]) / pr.w) / VAR1;
            float g[4] = {gx, gy, gw, gh};
            float4 ld = ((const float4*)arm_loc)[bp + c];
            float lds_[4] = {ld.x, ld.y, ld.z, ld.w};
            for (int q = 0; q < 4; ++q) {
                float d = lds_[q] - g[q];
                float ad = fabsf(d);
                ll += (ad < 1.0f) ? 0.5f * d * d : ad - 0.5f;
            }
        }
    }
    ((float4*)lcm)[bp >> 2] = make_float4(outv[0], outv[1], outv[2], outv[3]);
    for (int c = 0; c < 4; ++c) {
        unsigned bin = __float_as_uint(outv[c]) >> 20;   // < NB0 for finite >=0
        atomicAdd(&hc[bin], 1); atomicAdd(&hs[bin], outv[c]);
    }

    s1[tid] = ll; s2[tid] = plc; s3[tid] = np;
    __syncthreads();
    for (int i = tid; i < NB0; i += 256) {
        int cv = hc[i];
        if (cv) { atomicAdd(&Hc0[b * NB0 + i], cv); atomicAdd(&Hs0[b * NB0 + i], hs[i]); }
    }
    for (int st = 128; st > 0; st >>= 1) {
        if (tid < st) { s1[tid] += s1[tid+st]; s2[tid] += s2[tid+st]; s3[tid] += s3[tid+st]; }
        __syncthreads();
    }
    if (tid == 0) {
        pll[s * BB + b] = s1[0];
        pplc[s * BB + b] = s2[0];
        pnp[s * BB + b] = s3[0];
    }
}

// ---- K4: gather. Every block re-derives (deterministically, counts-only)
// the selected pass-0 bin + remainder + sum-above, then compacts its slice's
// candidates (elements whose top-11 bits == selected bin) into cand[]. ----
__global__ void __launch_bounds__(256)
k_gather(const float* __restrict__ lcm, const int* __restrict__ Hc0,
         const float* __restrict__ Hs0, const int* __restrict__ pnp,
         float* __restrict__ cand, int* __restrict__ ccnt,
         unsigned* __restrict__ spre, int* __restrict__ srem,
         float* __restrict__ ssum) {
    __shared__ int sc[256]; __shared__ float sf[256];
    __shared__ int s_chunk; __shared__ unsigned s_bin;
    int b = blockIdx.y, tid = threadIdx.x;
    const int* hc = Hc0 + b * NB0;
    const float* hsg = Hs0 + b * NB0;
    int c = 0; float f = 0.f;
    for (int i = 0; i < 8; ++i) { c += hc[tid * 8 + i]; f += hsg[tid * 8 + i]; }
    sc[tid] = c; sf[tid] = f;
    __syncthreads();
    for (int off = 1; off < 256; off <<= 1) {
        int cv = (tid + off < 256) ? sc[tid + off] : 0;
        float fv = (tid + off < 256) ? sf[tid + off] : 0.f;
        __syncthreads();
        sc[tid] += cv; sf[tid] += fv;
        __syncthreads();
    }
    int np = 0;
    for (int i = 0; i < SS; ++i) np += pnp[i * BB + b];
    int k = NEGPOS_I * np; if (k > PP - 1) k = PP - 1;   // k >= 1 (forced matches)
    int r = k;
    int nxt = (tid == 255) ? 0 : sc[tid + 1];
    if (sc[tid] >= r && nxt < r) s_chunk = tid;
    __syncthreads();
    if (tid == 0) {
        int ch = s_chunk;
        int r2 = r - ((ch == 255) ? 0 : sc[ch + 1]);
        float S2 = (ch == 255) ? 0.f : sf[ch + 1];
        int binSel = ch * 8;
        for (int i = 7; i >= 0; --i) {
            int bin = ch * 8 + i;
            int cb = hc[bin];
            if (r2 <= cb) { binSel = bin; break; }
            r2 -= cb; S2 += hsg[bin];
        }
        s_bin = (unsigned)binSel;
        if (blockIdx.x == 0) { spre[b] = (unsigned)binSel; srem[b] = r2; ssum[b] = S2; }
    }
    __syncthreads();
    unsigned bin0 = s_bin;
    const float4* v4 = (const float4*)(lcm + (size_t)b * PP);
    int base = blockIdx.x * 1024;
    int lane = tid & 63;
    for (int i = 0; i < 4; ++i) {
        float4 x = v4[base + i * 256 + tid];
        float xs[4] = {x.x, x.y, x.z, x.w};
        for (int c2 = 0; c2 < 4; ++c2) {
            bool mt = (__float_as_uint(xs[c2]) >> 20) == bin0;
            u64 bal = __ballot(mt);
            if (bal) {
                int leader = __ffsll((long long)bal) - 1;
                int cnt = __popcll(bal);
                int posi = __popcll(bal & ((1ull << lane) - 1ull));
                int basei = 0;
                if (lane == leader) basei = atomicAdd(&ccnt[b], cnt);
                basei = __shfl(basei, leader);
                if (mt) cand[(size_t)b * PP + basei + posi] = xs[c2];
            }
        }
    }
}

// ---- K5: per-batch block-local radix passes 1&2 over candidates ----
__global__ void __launch_bounds__(256)
k_select(const float* __restrict__ cand, const int* __restrict__ ccnt,
         const unsigned* __restrict__ spre, const int* __restrict__ srem,
         const float* __restrict__ ssum, float* __restrict__ topk) {
    __shared__ int hc[1024]; __shared__ float hs[1024];
    __shared__ int sc[256]; __shared__ float sf[256];
    __shared__ int s_chunk; __shared__ unsigned s_bin; __shared__ int s_r; __shared__ float s_S;
    int b = blockIdx.x, tid = threadIdx.x;
    int n = ccnt[b];
    const float* v = cand + (size_t)b * PP;
    unsigned pre0 = spre[b];
    if (tid == 0) { s_r = srem[b]; s_S = 0.f; }

    for (int pass = 0; pass < 2; ++pass) {
        for (int i = tid; i < 1024; i += 256) { hc[i] = 0; hs[i] = 0.f; }
        __syncthreads();
        unsigned b1 = s_bin;   // valid when pass==1
        for (int i = tid; i < n; i += 256) {
            float x = v[i];
            unsigned u = __float_as_uint(x);
            bool ok; unsigned bin;
            if (pass == 0) { ok = true;                       bin = (u >> 10) & 1023u; }
            else           { ok = ((u >> 10) & 1023u) == b1;  bin = u & 1023u; }
            if (ok) { atomicAdd(&hc[bin], 1); atomicAdd(&hs[bin], x); }
        }
        __syncthreads();
        int c = 0; float f = 0.f;
        for (int i = 0; i < 4; ++i) { c += hc[tid * 4 + i]; f += hs[tid * 4 + i]; }
        sc[tid] = c; sf[tid] = f;
        __syncthreads();
        for (int off = 1; off < 256; off <<= 1) {
            int cv = (tid + off < 256) ? sc[tid + off] : 0;
            float fv = (tid + off < 256) ? sf[tid + off] : 0.f;
            __syncthreads();
            sc[tid] += cv; sf[tid] += fv;
            __syncthreads();
        }
        int r = s_r;
        int nxt = (tid == 255) ? 0 : sc[tid + 1];
        if (sc[tid] >= r && nxt < r) s_chunk = tid;
        __syncthreads();
        if (tid == 0) {
            int ch = s_chunk;
            int r2 = r - ((ch == 255) ? 0 : sc[ch + 1]);
            float S2 = s_S + ((ch == 255) ? 0.f : sf[ch + 1]);
            int binSel = ch * 4;
            for (int i = 3; i >= 0; --i) {
                int bin = ch * 4 + i;
                int cb = hc[bin];
                if (r2 <= cb) { binSel = bin; break; }
                r2 -= cb; S2 += hs[bin];
            }
            s_bin = (unsigned)binSel; s_r = r2; s_S = S2;
        }
        __syncthreads();
    }
    if (tid == 0) {
        unsigned tb = (pre0 << 20) | ((unsigned)s_bin);  // bin2 in low bits
        // reconstruct: need bin1 too — carried via s_S/s_r bookkeeping below
        topk[b] = 0.f; // placeholder, real write after reconstruction
    }
    // NOTE: tval reconstruction needs both pass bins; redo cleanly:
    __shared__ unsigned s_b1, s_b2;
    // (s_bin currently holds bin2; we must have saved bin1.)
    // -- handled by storing bins in shared during the loop:
    (void)s_b1; (void)s_b2;
    if (tid == 0) {
        // s_prefix trick: rebuild from the select history kept in s_S/s_r is
        // not possible; instead recompute tval from stored bins:
        // we stored bin1 into s_bin at end of pass 0 and overwrote at pass 1.
        // To keep this correct we tracked the full prefix incrementally:
        // pass0 end: s_bin = bin1 ; pass1 end: s_bin = bin2.
        // Reconstruct bin1 from any candidate matching? Simpler: recover via
        // the value: threshold value tval must satisfy (u>>10)&1023 == bin1.
        // We saved nothing — so instead find one element with low-10 == bin2
        // and top-21 == (pre0<<... ) — overkill. Use s_b1 path below.
    }
    // The above reconstruction concern is resolved by the s_b1 capture here:
    // (executed during the loop via this trailing epilogue on re-entry)
    // -- see corrected logic in k_select_fix below (not used).
    if (tid == 0) topk[b] = ssum[b];  // overwritten by k_select2
}

// ---- K5b: corrected compact select (single kernel actually used) ----
__global__ void __launch_bounds__(256)
k_select2(const float* __restrict__ cand, const int* __restrict__ ccnt,
          const unsigned* __restrict__ spre, const int* __restrict__ srem,
          const float* __restrict__ ssum, float* __restrict__ topk) {
    __shared__ int hc[1024]; __shared__ float hs[1024];
    __shared__ int sc[256]; __shared__ float sf[256];
    __shared__ int s_chunk; __shared__ unsigned s_bins[2];
    __shared__ int s_r; __shared__ float s_S;
    int b = blockIdx.x, tid = threadIdx.x;
    int n = ccnt[b];
    const float* v = cand + (size_t)b * PP;
    unsigned pre0 = spre[b];
    if (tid == 0) { s_r = srem[b]; s_S = 0.f; }
    __syncthreads();

    for (int pass = 0; pass < 2; ++pass) {
        for (int i = tid; i < 1024; i += 256) { hc[i] = 0; hs[i] = 0.f; }
        __syncthreads();
        unsigned b1 = s_bins[0];
        for (int i = tid; i < n; i += 256) {
            float x = v[i];
            unsigned u = __float_as_uint(x);
            bool ok; unsigned bin;
            if (pass == 0) { ok = true;                       bin = (u >> 10) & 1023u; }
            else           { ok = ((u >> 10) & 1023u) == b1;  bin = u & 1023u; }
            if (ok) { atomicAdd(&hc[bin], 1); atomicAdd(&hs[bin], x); }
        }
        __syncthreads();
        int c = 0; float f = 0.f;
        for (int i = 0; i < 4; ++i) { c += hc[tid * 4 + i]; f += hs[tid * 4 + i]; }
        sc[tid] = c; sf[tid] = f;
        __syncthreads();
        for (int off = 1; off < 256; off <<= 1) {
            int cv = (tid + off < 256) ? sc[tid + off] : 0;
            float fv = (tid + off < 256) ? sf[tid + off] : 0.f;
            __syncthreads();
            sc[tid] += cv; sf[tid] += fv;
            __syncthreads();
        }
        int r = s_r;
        int nxt = (tid == 255) ? 0 : sc[tid + 1];
        if (sc[tid] >= r && nxt < r) s_chunk = tid;
        __syncthreads();
        if (tid == 0) {
            int ch = s_chunk;
            int r2 = r - ((ch == 255) ? 0 : sc[ch + 1]);
            float S2 = s_S + ((ch == 255) ? 0.f : sf[ch + 1]);
            int binSel = ch * 4;
            for (int i = 3; i >= 0; --i) {
                int bin = ch * 4 + i;
                int cb = hc[bin];
                if (r2 <= cb) { binSel = bin; break; }
                r2 -= cb; S2 += hs[bin];
            }
            s_bins[pass] = (unsigned)binSel; s_r = r2; s_S = S2;
        }
        __syncthreads();
    }
    if (tid == 0) {
        unsigned tb = (pre0 << 20) | (s_bins[0] << 10) | s_bins[1];
        topk[b] = ssum[b] + s_S + (float)s_r * __uint_as_float(tb);
    }
}

// ---- K6: final reduction across batches -> (loss_l/N, loss_c/N) ----
__global__ void k_final(const float* __restrict__ pll, const float* __restrict__ pplc,
                        const int* __restrict__ pnp, const float* __restrict__ topk,
                        float* __restrict__ out) {
    int b = threadIdx.x;          // 64 threads = one wave, one batch each
    float ll = 0.f, plc = 0.f; int np = 0;
    for (int s = 0; s < SS; ++s) {
        ll += pll[s * BB + b];
        plc += pplc[s * BB + b];
        np += pnp[s * BB + b];
    }
    float cc = plc + topk[b];
    for (int s = 32; s > 0; s >>= 1) {
        ll += __shfl_down(ll, s);
        cc += __shfl_down(cc, s);
        np += __shfl_down(np, s);
    }
    if (b == 0) {
        float N = (float)np;
        out[0] = ll / N;
        out[1] = cc / N;
    }
}

extern "C" void kernel_launch(void* const* d_in, const int* in_sizes, int n_in,
                              void* d_out, int out_size, void* d_ws, size_t ws_size,
                              hipStream_t stream) {
    const float* arm_loc  = (const float*)d_in[0];
    const float* arm_conf = (const float*)d_in[1];
    const float* priors   = (const float*)d_in[4];
    const float* targets  = (const float*)d_in[5];
    float* out = (float*)d_out;

    char* w = (char*)d_ws;
    float* bto = (float*)w;  w += sizeof(float) * (size_t)BB * PP;    // 8 MB
    int*   bti = (int*)w;    w += sizeof(int)   * (size_t)BB * PP;    // 8 MB
    float* lcm = (float*)w;  w += sizeof(float) * (size_t)BB * PP;    // 8 MB
    float* cand = bto;       // aliased: bto fully consumed before k_gather
    // ---- zeroed region (atomically accumulated) ----
    char* zbase = w;
    int*   Hc0 = (int*)w;    w += sizeof(int)   * BB * NB0;           // 512 KB
    float* Hs0 = (float*)w;  w += sizeof(float) * BB * NB0;           // 512 KB
    u64*   bpm = (u64*)w;    w += sizeof(u64)   * BB * OO;
    int*   ccnt = (int*)w;   w += sizeof(int)   * BB;
    size_t zbytes = (size_t)(w - zbase);
    // ---- plain written-before-read region ----
    float* pll  = (float*)w; w += sizeof(float) * BB * SS;
    float* pplc = (float*)w; w += sizeof(float) * BB * SS;
    int*   pnp  = (int*)w;   w += sizeof(int)   * BB * SS;
    unsigned* spre = (unsigned*)w; w += sizeof(unsigned) * BB;
    int*      srem = (int*)w;      w += sizeof(int) * BB;
    float*    ssum = (float*)w;    w += sizeof(float) * BB;
    float*    topk = (float*)w;    w += sizeof(float) * BB;

    int n4 = (int)(zbytes / 16);
    k_zero<<<(n4 + 255) / 256, 256, 0, stream>>>((float4*)zbase, n4);
    k_match<<<dim3(PP / (256 * T1), BB), 256, 0, stream>>>(priors, targets, bto, bti, bpm);
    k_force<<<BB, 64, 0, stream>>>(bpm, bto, bti);
    k_loss<<<dim3(SS, BB), 256, 0, stream>>>(arm_loc, arm_conf, priors, targets,
                                             bto, bti, lcm, pll, pplc, pnp, Hc0, Hs0);
    k_gather<<<dim3(8, BB), 256, 0, stream>>>(lcm, Hc0, Hs0, pnp, cand, ccnt,
                                              spre, srem, ssum);
    k_select2<<<BB, 256, 0, stream>>>(cand, ccnt, spre, srem, ssum, topk);
    k_final<<<1, 64, 0, stream>>>(pll, pplc, pnp, topk, out);
}

// Round 5
// 290.025 us; speedup vs baseline: 1.3157x; 1.3157x over previous
//
#include <hip/hip_runtime.h>
#include <cstdint>

#pragma clang fp contract(off)

#define BB 64
#define PP 32768
#define OO 50
#define THRESH_F 0.5f
#define VAR0 0.1f
#define VAR1 0.2f
#define NEGPOS_I 3
#define SS 32            // k_loss splits per batch
#define T1 8             // priors per thread in k_match
#define NB0 2048         // pass-0 bins (bits 30:20, sign always 0)

typedef unsigned long long u64;

// ---- K0: zero bpm (atomically max-reduced) ----
__global__ void k_zero(float4* __restrict__ dst, int n4) {
    int i = blockIdx.x * blockDim.x + threadIdx.x;
    if (i < n4) dst[i] = make_float4(0.f, 0.f, 0.f, 0.f);
}

// ---- K1: fused matcher. Row-best per prior (regs) + column-best per truth
// (wave u64 max-reduce -> one global atomicMax per wave per truth; no return
// value is read, so no latency chain). Packing (iou_bits<<32)|(PP-p).
__global__ void __launch_bounds__(256)
k_match(const float* __restrict__ priors, const float* __restrict__ targets,
        float* __restrict__ bto, int* __restrict__ bti, u64* __restrict__ bpm) {
    __shared__ float tr4[OO * 4];
    __shared__ float trA[OO];
    int b = blockIdx.y, tid = threadIdx.x;
    for (int i = tid; i < OO * 4; i += 256)
        tr4[i] = targets[(size_t)(b * OO + (i >> 2)) * 5 + (i & 3)];
    __syncthreads();
    if (tid < OO)
        trA[tid] = (tr4[tid*4+2] - tr4[tid*4]) * (tr4[tid*4+3] - tr4[tid*4+1]);
    __syncthreads();

    int p0 = blockIdx.x * (256 * T1) + tid * T1;
    float bx0[T1], by0[T1], bx1[T1], by1[T1], aB[T1];
    for (int j = 0; j < T1; ++j) {
        float4 pr = ((const float4*)priors)[p0 + j];
        bx0[j] = pr.x - pr.z * 0.5f; by0[j] = pr.y - pr.w * 0.5f;
        bx1[j] = pr.x + pr.z * 0.5f; by1[j] = pr.y + pr.w * 0.5f;
        aB[j] = (bx1[j] - bx0[j]) * (by1[j] - by0[j]);
    }
    float rbv[T1]; int rbi[T1];
    for (int j = 0; j < T1; ++j) { rbv[j] = -1.0f; rbi[j] = 0; }

    for (int t = 0; t < OO; ++t) {
        float t0 = tr4[t*4], t1v = tr4[t*4+1], t2 = tr4[t*4+2], t3 = tr4[t*4+3];
        float aA = trA[t];
        float cbv = -1.0f; int cbp = 0;
        for (int j = 0; j < T1; ++j) {
            float ltx = fmaxf(t0, bx0[j]), lty = fmaxf(t1v, by0[j]);
            float rbx = fminf(t2, bx1[j]), rby = fminf(t3, by1[j]);
            float wx = fmaxf(rbx - ltx, 0.f), wy = fmaxf(rby - lty, 0.f);
            float inter = wx * wy;
            float uni = aA + aB[j] - inter;
            float v = inter * __builtin_amdgcn_rcpf(uni);
            if (v > rbv[j]) { rbv[j] = v; rbi[j] = t; }   // row: first-max
            if (v > cbv) { cbv = v; cbp = p0 + j; }       // col: smallest p
        }
        u64 pk = ((u64)__float_as_uint(cbv) << 32) | (unsigned)(PP - cbp);
        for (int s = 32; s >= 1; s >>= 1) {
            u64 o = __shfl_xor(pk, s, 64);
            if (o > pk) pk = o;
        }
        if ((tid & 63) == 0) atomicMax(&bpm[b * OO + t], pk);
    }
    size_t bp = (size_t)b * PP + p0;
    ((float4*)bto)[bp >> 2]       = make_float4(rbv[0], rbv[1], rbv[2], rbv[3]);
    ((float4*)bto)[(bp >> 2) + 1] = make_float4(rbv[4], rbv[5], rbv[6], rbv[7]);
    ((int4*)bti)[bp >> 2]         = make_int4(rbi[0], rbi[1], rbi[2], rbi[3]);
    ((int4*)bti)[(bp >> 2) + 1]   = make_int4(rbi[4], rbi[5], rbi[6], rbi[7]);
}

// ---- K2: forced match — sequential per batch, last write wins ----
__global__ void k_force(const u64* __restrict__ bpm,
                        float* __restrict__ bto, int* __restrict__ bti) {
    __shared__ int pidx[OO];
    int b = blockIdx.x, tid = threadIdx.x;
    if (tid < OO) pidx[tid] = PP - (int)(unsigned)(bpm[b * OO + tid] & 0xFFFFFFFFull);
    __syncthreads();
    if (tid == 0) {
        for (int j = 0; j < OO; ++j) {
            int p = pidx[j];
            bto[(size_t)b * PP + p] = 2.0f;
            bti[(size_t)b * PP + p] = j;
        }
    }
}

// ---- K3: conf/encode/smooth-L1/lc; writes lcm + per-block partials ----
__global__ void __launch_bounds__(256)
k_loss(const float* __restrict__ arm_loc, const float* __restrict__ arm_conf,
       const float* __restrict__ priors, const float* __restrict__ targets,
       const float* __restrict__ bto, const int* __restrict__ bti,
       float* __restrict__ lcm, float* __restrict__ pll,
       float* __restrict__ pplc, int* __restrict__ pnp) {
    int b = blockIdx.y, s = blockIdx.x, tid = threadIdx.x;
    int p = s * 1024 + tid * 4;
    size_t bp = (size_t)b * PP + p;

    float4 ov4 = ((const float4*)bto)[bp >> 2];
    int4   ti4 = ((const int4*)bti)[bp >> 2];
    float4 ca  = ((const float4*)arm_conf)[bp >> 1];
    float4 cb  = ((const float4*)arm_conf)[(bp >> 1) + 1];
    float ovs[4] = {ov4.x, ov4.y, ov4.z, ov4.w};
    int   tis[4] = {ti4.x, ti4.y, ti4.z, ti4.w};
    float cs[8]  = {ca.x, ca.y, ca.z, ca.w, cb.x, cb.y, cb.z, cb.w};

    float ll = 0.0f, plc = 0.0f; int np = 0;
    float outv[4];
    for (int c = 0; c < 4; ++c) {
        int ti = tis[c];
        const float* tb = &targets[(size_t)(b * OO + ti) * 5];
        int label = (tb[4] >= 0.0f) ? 1 : 0;
        int conf = (ovs[c] < THRESH_F) ? 0 : label;
        float c0 = cs[c * 2], c1 = cs[c * 2 + 1];
        float m = fmaxf(c0, c1);
        // identical to log(exp(c0-m)+exp(c1-m))+m: max term is expf(0)==1
        float lse = __logf(1.0f + __expf(-fabsf(c0 - c1))) + m;
        float picked = (conf == 1) ? c1 : c0;
        float lc = lse - picked;
        bool pos = conf > 0;
        outv[c] = pos ? 0.0f : lc;
        if (pos) {
            np++; plc += lc;
            float4 pr = ((const float4*)priors)[p + c];
            float gx = ((tb[0] + tb[2]) * 0.5f - pr.x) / (VAR0 * pr.z);
            float gy = ((tb[1] + tb[3]) * 0.5f - pr.y) / (VAR0 * pr.w);
            float gw = __logf((tb[2] - tb[0]) / pr.z) / VAR1;
            float gh = __logf((tb[3] - tb[1]) / pr.w) / VAR1;
            float g[4] = {gx, gy, gw, gh};
            float4 ld = ((const float4*)arm_loc)[bp + c];
            float lds_[4] = {ld.x, ld.y, ld.z, ld.w};
            for (int q = 0; q < 4; ++q) {
                float d = lds_[q] - g[q];
                float ad = fabsf(d);
                ll += (ad < 1.0f) ? 0.5f * d * d : ad - 0.5f;
            }
        }
    }
    ((float4*)lcm)[bp >> 2] = make_float4(outv[0], outv[1], outv[2], outv[3]);

    __shared__ float s1[256], s2[256]; __shared__ int s3[256];
    s1[tid] = ll; s2[tid] = plc; s3[tid] = np;
    __syncthreads();
    for (int st = 128; st > 0; st >>= 1) {
        if (tid < st) { s1[tid] += s1[tid+st]; s2[tid] += s2[tid+st]; s3[tid] += s3[tid+st]; }
        __syncthreads();
    }
    if (tid == 0) {
        pll[s * BB + b] = s1[0];
        pplc[s * BB + b] = s2[0];
        pnp[s * BB + b] = s3[0];
    }
}

// ---- K4: per-batch exact top-k sum, one block per batch, 3 radix passes
// (11/10/10 bits) over the batch's L2-resident 128 KB lcm slice. LDS-only
// histograms (counts + value sums); pass 0 uses 4 per-wave copies to kill
// clustered-exponent same-bin atomic serialization. No global atomics. ----
__global__ void __launch_bounds__(256)
k_topk(const float* __restrict__ lcm, const int* __restrict__ pnp,
       float* __restrict__ topk) {
    __shared__ int   hc[4][NB0];
    __shared__ float hs[4][NB0];
    __shared__ int sc[256]; __shared__ float sf[256];
    __shared__ int s_chunk;
    __shared__ unsigned s_pre; __shared__ int s_r; __shared__ float s_S;
    int b = blockIdx.x, tid = threadIdx.x;
    int w4 = (tid >> 6) & 3;

    for (int i = tid; i < NB0; i += 256) {
        hc[0][i] = 0; hc[1][i] = 0; hc[2][i] = 0; hc[3][i] = 0;
        hs[0][i] = 0.f; hs[1][i] = 0.f; hs[2][i] = 0.f; hs[3][i] = 0.f;
    }
    __syncthreads();

    const float4* v4 = (const float4*)(lcm + (size_t)b * PP);
    for (int i = tid; i < PP / 4; i += 256) {
        float4 x = v4[i];
        float xs[4] = {x.x, x.y, x.z, x.w};
        for (int c = 0; c < 4; ++c) {
            unsigned bin = __float_as_uint(xs[c]) >> 20;  // < 2048 (finite >= 0)
            atomicAdd(&hc[w4][bin], 1);
            atomicAdd(&hs[w4][bin], xs[c]);
        }
    }
    __syncthreads();

    int np = 0;
    for (int i = 0; i < SS; ++i) np += pnp[i * BB + b];
    int k = NEGPOS_I * np; if (k > PP - 1) k = PP - 1;
    if (k <= 0) { if (tid == 0) topk[b] = 0.f; return; }

    // ---- pass-0 scan/select (collapse 4 copies; 8 bins/thread) ----
    {
        int c = 0; float f = 0.f;
        for (int i = 0; i < 8; ++i) {
            int bin = tid * 8 + i;
            int cc = hc[0][bin] + hc[1][bin] + hc[2][bin] + hc[3][bin];
            float ff = hs[0][bin] + hs[1][bin] + hs[2][bin] + hs[3][bin];
            hc[0][bin] = cc; hs[0][bin] = ff;   // own bins only: no race
            c += cc; f += ff;
        }
        sc[tid] = c; sf[tid] = f;
    }
    __syncthreads();
    for (int off = 1; off < 256; off <<= 1) {
        int cv = (tid + off < 256) ? sc[tid + off] : 0;
        float fv = (tid + off < 256) ? sf[tid + off] : 0.f;
        __syncthreads();
        sc[tid] += cv; sf[tid] += fv;
        __syncthreads();
    }
    {
        int r = k;
        int nxt = (tid == 255) ? 0 : sc[tid + 1];
        if (sc[tid] >= r && nxt < r) s_chunk = tid;
        __syncthreads();
        if (tid == 0) {
            int ch = s_chunk;
            int r2 = r - ((ch == 255) ? 0 : sc[ch + 1]);
            float S2 = (ch == 255) ? 0.f : sf[ch + 1];
            int binSel = ch * 8;
            for (int i = 7; i >= 0; --i) {
                int bin = ch * 8 + i;
                int cb = hc[0][bin];
                if (r2 <= cb) { binSel = bin; break; }
                r2 -= cb; S2 += hs[0][bin];
            }
            s_pre = (unsigned)binSel; s_r = r2; s_S = S2;
        }
    }
    __syncthreads();

    // ---- passes 1 & 2: 10-bit digits, single-copy 1024-bin hist ----
    for (int pass = 1; pass <= 2; ++pass) {
        for (int i = tid; i < 1024; i += 256) { hc[0][i] = 0; hs[0][i] = 0.f; }
        __syncthreads();
        unsigned pre = s_pre;
        int sh = (pass == 1) ? 10 : 0;
        for (int i = tid; i < PP / 4; i += 256) {
            float4 x = v4[i];
            float xs[4] = {x.x, x.y, x.z, x.w};
            for (int c = 0; c < 4; ++c) {
                unsigned u = __float_as_uint(xs[c]);
                if ((u >> (sh + 10)) == pre) {
                    unsigned bin = (u >> sh) & 1023u;
                    atomicAdd(&hc[0][bin], 1);
                    atomicAdd(&hs[0][bin], xs[c]);
                }
            }
        }
        __syncthreads();
        {
            int c = 0; float f = 0.f;
            for (int i = 0; i < 4; ++i) { c += hc[0][tid * 4 + i]; f += hs[0][tid * 4 + i]; }
            sc[tid] = c; sf[tid] = f;
        }
        __syncthreads();
        for (int off = 1; off < 256; off <<= 1) {
            int cv = (tid + off < 256) ? sc[tid + off] : 0;
            float fv = (tid + off < 256) ? sf[tid + off] : 0.f;
            __syncthreads();
            sc[tid] += cv; sf[tid] += fv;
            __syncthreads();
        }
        int rr = s_r;
        int nx = (tid == 255) ? 0 : sc[tid + 1];
        if (sc[tid] >= rr && nx < rr) s_chunk = tid;
        __syncthreads();
        if (tid == 0) {
            int ch = s_chunk;
            int r2 = rr - ((ch == 255) ? 0 : sc[ch + 1]);
            float S2 = s_S + ((ch == 255) ? 0.f : sf[ch + 1]);
            int binSel = ch * 4;
            for (int i = 3; i >= 0; --i) {
                int bin = ch * 4 + i;
                int cb = hc[0][bin];
                if (r2 <= cb) { binSel = bin; break; }
                r2 -= cb; S2 += hs[0][bin];
            }
            s_pre = (s_pre << 10) | (unsigned)binSel; s_r = r2; s_S = S2;
        }
        __syncthreads();
    }
    if (tid == 0)
        topk[b] = s_S + (float)s_r * __uint_as_float(s_pre);
}

// ---- K5: final reduction across batches -> (loss_l/N, loss_c/N) ----
__global__ void k_final(const float* __restrict__ pll, const float* __restrict__ pplc,
                        const int* __restrict__ pnp, const float* __restrict__ topk,
                        float* __restrict__ out) {
    int b = threadIdx.x;          // 64 threads = one wave, one batch each
    float ll = 0.f, plc = 0.f; int np = 0;
    for (int s = 0; s < SS; ++s) {
        ll += pll[s * BB + b];
        plc += pplc[s * BB + b];
        np += pnp[s * BB + b];
    }
    float cc = plc + topk[b];
    for (int s = 32; s > 0; s >>= 1) {
        ll += __shfl_down(ll, s);
        cc += __shfl_down(cc, s);
        np += __shfl_down(np, s);
    }
    if (b == 0) {
        float N = (float)np;
        out[0] = ll / N;
        out[1] = cc / N;
    }
}

extern "C" void kernel_launch(void* const* d_in, const int* in_sizes, int n_in,
                              void* d_out, int out_size, void* d_ws, size_t ws_size,
                              hipStream_t stream) {
    const float* arm_loc  = (const float*)d_in[0];
    const float* arm_conf = (const float*)d_in[1];
    const float* priors   = (const float*)d_in[4];
    const float* targets  = (const float*)d_in[5];
    float* out = (float*)d_out;

    char* w = (char*)d_ws;
    float* bto = (float*)w;  w += sizeof(float) * (size_t)BB * PP;    // 8 MB
    int*   bti = (int*)w;    w += sizeof(int)   * (size_t)BB * PP;    // 8 MB
    float* lcm = (float*)w;  w += sizeof(float) * (size_t)BB * PP;    // 8 MB
    // ---- zeroed region (atomicMax-accumulated) ----
    char* zbase = w;
    u64*   bpm = (u64*)w;    w += sizeof(u64)   * BB * OO;
    size_t zbytes = (size_t)(w - zbase);
    // ---- plain written-before-read region ----
    float* pll  = (float*)w; w += sizeof(float) * BB * SS;
    float* pplc = (float*)w; w += sizeof(float) * BB * SS;
    int*   pnp  = (int*)w;   w += sizeof(int)   * BB * SS;
    float* topk = (float*)w; w += sizeof(float) * BB;

    int n4 = (int)(zbytes / 16);
    k_zero<<<(n4 + 255) / 256, 256, 0, stream>>>((float4*)zbase, n4);
    k_match<<<dim3(PP / (256 * T1), BB), 256, 0, stream>>>(priors, targets, bto, bti, bpm);
    k_force<<<BB, 64, 0, stream>>>(bpm, bto, bti);
    k_loss<<<dim3(SS, BB), 256, 0, stream>>>(arm_loc, arm_conf, priors, targets,
                                             bto, bti, lcm, pll, pplc, pnp);
    k_topk<<<BB, 256, 0, stream>>>(lcm, pnp, topk);
    k_final<<<1, 64, 0, stream>>>(pll, pplc, pnp, topk, out);
}

// Round 6
// 287.322 us; speedup vs baseline: 1.3280x; 1.0094x over previous
//
#include <hip/hip_runtime.h>
#include <cstdint>

#pragma clang fp contract(off)

#define BB 64
#define PP 32768
#define OO 50
#define VAR0 0.1f
#define VAR1 0.2f
#define NEGPOS_I 3
#define SS 32            // k_loss splits per batch
#define T1 8             // priors per thread in k_match
#define NBH 4096         // hist bins: bits 30:19 (12 bits; bit31 always 0)
#define SCAP 8192        // survivor capacity in k_resolve LDS

typedef unsigned long long u64;

// ---- K0: zero bpm + global histograms ----
__global__ void k_zero(float4* __restrict__ dst, int n4) {
    int i = blockIdx.x * blockDim.x + threadIdx.x;
    if (i < n4) dst[i] = make_float4(0.f, 0.f, 0.f, 0.f);
}

// ---- K1: fused matcher, division-free. Bests kept as (inter, uni) pairs;
// a/b > c/d <=> a*d > c*b (all positive). One rcp per wave per truth (the
// column winner) for the atomicMax packing. bto = pos flag (2*I >= U, exact).
__global__ void __launch_bounds__(256)
k_match(const float* __restrict__ priors, const float* __restrict__ targets,
        float* __restrict__ bto, int* __restrict__ bti, u64* __restrict__ bpm) {
    __shared__ float tr4[OO * 4];
    __shared__ float trA[OO];
    int b = blockIdx.y, tid = threadIdx.x;
    for (int i = tid; i < OO * 4; i += 256)
        tr4[i] = targets[(size_t)(b * OO + (i >> 2)) * 5 + (i & 3)];
    __syncthreads();
    if (tid < OO)
        trA[tid] = (tr4[tid*4+2] - tr4[tid*4]) * (tr4[tid*4+3] - tr4[tid*4+1]);
    __syncthreads();

    int p0 = blockIdx.x * (256 * T1) + tid * T1;
    float bx0[T1], by0[T1], bx1[T1], by1[T1], aB[T1];
    for (int j = 0; j < T1; ++j) {
        float4 pr = ((const float4*)priors)[p0 + j];
        bx0[j] = pr.x - pr.z * 0.5f; by0[j] = pr.y - pr.w * 0.5f;
        bx1[j] = pr.x + pr.z * 0.5f; by1[j] = pr.y + pr.w * 0.5f;
        aB[j] = (bx1[j] - bx0[j]) * (by1[j] - by0[j]);
    }
    float rbI[T1], rbU[T1]; int rbi[T1];
    for (int j = 0; j < T1; ++j) { rbI[j] = -1.0f; rbU[j] = 1.0f; rbi[j] = 0; }

    int lane = tid & 63;
    for (int t = 0; t < OO; ++t) {
        float t0 = tr4[t*4], t1v = tr4[t*4+1], t2 = tr4[t*4+2], t3 = tr4[t*4+3];
        float aA = trA[t];
        float cbI = -1.0f, cbU = 1.0f; int cbp = p0;
        for (int j = 0; j < T1; ++j) {
            float ltx = fmaxf(t0, bx0[j]), lty = fmaxf(t1v, by0[j]);
            float rbx = fminf(t2, bx1[j]), rby = fminf(t3, by1[j]);
            float wx = fmaxf(rbx - ltx, 0.f), wy = fmaxf(rby - lty, 0.f);
            float inter = wx * wy;
            float uni = (aA + aB[j]) - inter;
            // row best: first-max (strict >)
            if (inter * rbU[j] > rbI[j] * uni) { rbI[j] = inter; rbU[j] = uni; rbi[j] = t; }
            // col best: smallest p on ties (strict >, ascending j)
            if (inter * cbU > cbI * uni) { cbI = inter; cbU = uni; cbp = p0 + j; }
        }
        // wave reduce the column candidate (prefer larger ratio, then smaller p)
        for (int s = 32; s >= 1; s >>= 1) {
            float oI = __shfl_xor(cbI, s, 64);
            float oU = __shfl_xor(cbU, s, 64);
            int   op = __shfl_xor(cbp, s, 64);
            float l = oI * cbU, r = cbI * oU;
            bool take = (l > r) || (l == r && op < cbp);
            if (take) { cbI = oI; cbU = oU; cbp = op; }
        }
        if (lane == 0) {
            float v = cbI * __builtin_amdgcn_rcpf(cbU);
            u64 pk = ((u64)__float_as_uint(v) << 32) | (unsigned)(PP - cbp);
            atomicMax(&bpm[b * OO + t], pk);
        }
    }
    float fl[T1];
    for (int j = 0; j < T1; ++j)
        fl[j] = (rbI[j] + rbI[j] >= rbU[j]) ? 1.0f : 0.0f;   // exact iou>=0.5 test
    size_t bp = (size_t)b * PP + p0;
    ((float4*)bto)[bp >> 2]       = make_float4(fl[0], fl[1], fl[2], fl[3]);
    ((float4*)bto)[(bp >> 2) + 1] = make_float4(fl[4], fl[5], fl[6], fl[7]);
    ((int4*)bti)[bp >> 2]         = make_int4(rbi[0], rbi[1], rbi[2], rbi[3]);
    ((int4*)bti)[(bp >> 2) + 1]   = make_int4(rbi[4], rbi[5], rbi[6], rbi[7]);
}

// ---- K2: forced match, parallel. Last-write-wins of the sequential loop ==
// among duplicate priors the LARGEST truth index j wins. ----
__global__ void k_force(const u64* __restrict__ bpm,
                        float* __restrict__ bto, int* __restrict__ bti) {
    __shared__ int pidx[OO];
    int b = blockIdx.x, tid = threadIdx.x;
    if (tid < OO) pidx[tid] = PP - (int)(unsigned)(bpm[b * OO + tid] & 0xFFFFFFFFull);
    __syncthreads();
    if (tid < OO) {
        int p = pidx[tid];
        bool win = true;
        for (int j2 = tid + 1; j2 < OO; ++j2)
            if (pidx[j2] == p) { win = false; break; }
        if (win) {
            bto[(size_t)b * PP + p] = 1.0f;
            bti[(size_t)b * PP + p] = tid;
        }
    }
}

// ---- K3: conf/encode/smooth-L1/lc; writes lcm + per-block partials ----
__global__ void __launch_bounds__(256)
k_loss(const float* __restrict__ arm_loc, const float* __restrict__ arm_conf,
       const float* __restrict__ priors, const float* __restrict__ targets,
       const float* __restrict__ bto, const int* __restrict__ bti,
       float* __restrict__ lcm, float* __restrict__ pll,
       float* __restrict__ pplc, int* __restrict__ pnp) {
    int b = blockIdx.y, s = blockIdx.x, tid = threadIdx.x;
    int p = s * 1024 + tid * 4;
    size_t bp = (size_t)b * PP + p;

    float4 ov4 = ((const float4*)bto)[bp >> 2];
    int4   ti4 = ((const int4*)bti)[bp >> 2];
    float4 ca  = ((const float4*)arm_conf)[bp >> 1];
    float4 cb  = ((const float4*)arm_conf)[(bp >> 1) + 1];
    float ovs[4] = {ov4.x, ov4.y, ov4.z, ov4.w};
    int   tis[4] = {ti4.x, ti4.y, ti4.z, ti4.w};
    float cs[8]  = {ca.x, ca.y, ca.z, ca.w, cb.x, cb.y, cb.z, cb.w};

    float ll = 0.0f, plc = 0.0f; int np = 0;
    float outv[4];
    for (int c = 0; c < 4; ++c) {
        int ti = tis[c];
        const float* tb = &targets[(size_t)(b * OO + ti) * 5];
        int label = (tb[4] >= 0.0f) ? 1 : 0;
        int conf = (ovs[c] != 0.0f) ? label : 0;      // ovs is the pos flag
        float c0 = cs[c * 2], c1 = cs[c * 2 + 1];
        float m = fmaxf(c0, c1);
        float lse = __logf(1.0f + __expf(-fabsf(c0 - c1))) + m;
        float picked = (conf == 1) ? c1 : c0;
        float lc = lse - picked;
        bool pos = conf > 0;
        outv[c] = pos ? 0.0f : lc;
        if (pos) {
            np++; plc += lc;
            float4 pr = ((const float4*)priors)[p + c];
            float gx = ((tb[0] + tb[2]) * 0.5f - pr.x) / (VAR0 * pr.z);
            float gy = ((tb[1] + tb[3]) * 0.5f - pr.y) / (VAR0 * pr.w);
            float gw = __logf((tb[2] - tb[0]) / pr.z) / VAR1;
            float gh = __logf((tb[3] - tb[1]) / pr.w) / VAR1;
            float g[4] = {gx, gy, gw, gh};
            float4 ld = ((const float4*)arm_loc)[bp + c];
            float lds_[4] = {ld.x, ld.y, ld.z, ld.w};
            for (int q = 0; q < 4; ++q) {
                float d = lds_[q] - g[q];
                float ad = fabsf(d);
                ll += (ad < 1.0f) ? 0.5f * d * d : ad - 0.5f;
            }
        }
    }
    ((float4*)lcm)[bp >> 2] = make_float4(outv[0], outv[1], outv[2], outv[3]);

    __shared__ float s1[256], s2[256]; __shared__ int s3[256];
    s1[tid] = ll; s2[tid] = plc; s3[tid] = np;
    __syncthreads();
    for (int st = 128; st > 0; st >>= 1) {
        if (tid < st) { s1[tid] += s1[tid+st]; s2[tid] += s2[tid+st]; s3[tid] += s3[tid+st]; }
        __syncthreads();
    }
    if (tid == 0) {
        pll[s * BB + b] = s1[0];
        pplc[s * BB + b] = s2[0];
        pnp[s * BB + b] = s3[0];
    }
}

// ---- K4a: decorrelated 12-bit histogram (bits 30:19), counts + value sums.
// LDS pre-aggregate per block, then <=1 global atomic per nonzero bin. ----
__global__ void __launch_bounds__(256)
k_hist(const float* __restrict__ lcm, int* __restrict__ Hc, float* __restrict__ Hs) {
    __shared__ int hc[NBH]; __shared__ float hs[NBH];
    int b = blockIdx.y, tid = threadIdx.x;
    for (int i = tid; i < NBH; i += 256) { hc[i] = 0; hs[i] = 0.f; }
    __syncthreads();
    const float4* v4 = (const float4*)(lcm + (size_t)b * PP);
    int base = blockIdx.x * 1024;
    for (int it = 0; it < 4; ++it) {
        float4 x = v4[base + it * 256 + tid];
        float xs[4] = {x.x, x.y, x.z, x.w};
        for (int c = 0; c < 4; ++c) {
            unsigned bin = __float_as_uint(xs[c]) >> 19;   // < NBH (finite >= 0)
            atomicAdd(&hc[bin], 1);
            atomicAdd(&hs[bin], xs[c]);
        }
    }
    __syncthreads();
    for (int i = tid; i < NBH; i += 256) {
        int cv = hc[i];
        if (cv) { atomicAdd(&Hc[b * NBH + i], cv); atomicAdd(&Hs[b * NBH + i], hs[i]); }
    }
}

// Shared-memory suffix-scan + k-th-largest bin selection over nb bins.
// On entry *s_r / *s_S hold remainder & sum-above; on exit updated, *s_bin set.
__device__ __forceinline__ void suffix_select(
    int nb, int* hc, float* hs, int* sc, float* sf,
    int* s_chunk, int* s_r, float* s_S, unsigned* s_bin, int tid) {
    int per = nb >> 8;
    int c = 0; float f = 0.f;
    int base = tid * per;
    for (int i = 0; i < per; ++i) { c += hc[base + i]; f += hs[base + i]; }
    sc[tid] = c; sf[tid] = f;
    __syncthreads();
    for (int off = 1; off < 256; off <<= 1) {
        int cv = (tid + off < 256) ? sc[tid + off] : 0;
        float fv = (tid + off < 256) ? sf[tid + off] : 0.f;
        __syncthreads();
        sc[tid] += cv; sf[tid] += fv;
        __syncthreads();
    }
    int r = *s_r;
    int nxt = (tid == 255) ? 0 : sc[tid + 1];
    if (sc[tid] >= r && nxt < r) *s_chunk = tid;
    __syncthreads();
    if (tid == 0) {
        int ch = *s_chunk;
        int r2 = r - ((ch == 255) ? 0 : sc[ch + 1]);
        float S2 = *s_S + ((ch == 255) ? 0.f : sf[ch + 1]);
        int binSel = ch * per;
        for (int i = per - 1; i >= 0; --i) {
            int bin = ch * per + i;
            int cb = hc[bin];
            if (r2 <= cb) { binSel = bin; break; }
            r2 -= cb; S2 += hs[bin];
        }
        *s_bin = (unsigned)binSel; *s_r = r2; *s_S = S2;
    }
    __syncthreads();
}

// ---- K4b: per-batch resolve: select 12-bit bin, compact survivors to LDS,
// two tiny LDS radix passes (bits 18:9, 8:0). Global-read fallback if the
// survivor buffer would overflow (exactness preserved in all cases). ----
__global__ void __launch_bounds__(256)
k_resolve(const float* __restrict__ lcm, const int* __restrict__ pnp,
          const int* __restrict__ Hc, const float* __restrict__ Hs,
          float* __restrict__ topk) {
    __shared__ int hc[NBH]; __shared__ float hsv[NBH];
    __shared__ float sbuf[SCAP];
    __shared__ int sc[256]; __shared__ float sf[256];
    __shared__ int s_chunk, s_r, s_cnt; __shared__ float s_S; __shared__ unsigned s_bin;
    int b = blockIdx.x, tid = threadIdx.x;

    int np = 0;
    for (int i = 0; i < SS; ++i) np += pnp[i * BB + b];
    int k = NEGPOS_I * np; if (k > PP - 1) k = PP - 1;
    if (k <= 0) { if (tid == 0) topk[b] = 0.f; return; }

    for (int i = tid; i < NBH; i += 256) { hc[i] = Hc[b*NBH+i]; hsv[i] = Hs[b*NBH+i]; }
    if (tid == 0) { s_r = k; s_S = 0.f; s_cnt = 0; }
    __syncthreads();
    suffix_select(NBH, hc, hsv, sc, sf, &s_chunk, &s_r, &s_S, &s_bin, tid);
    unsigned bin1 = s_bin;

    // compact survivors (top-12-bits == bin1) into LDS
    const float4* v4 = (const float4*)(lcm + (size_t)b * PP);
    int lane = tid & 63;
    for (int i = tid; i < PP / 4; i += 256) {
        float4 x = v4[i];
        float xs[4] = {x.x, x.y, x.z, x.w};
        for (int c = 0; c < 4; ++c) {
            bool mt = (__float_as_uint(xs[c]) >> 19) == bin1;
            u64 bal = __ballot(mt);
            if (bal) {
                int leader = __ffsll((long long)bal) - 1;
                int cnt = __popcll(bal);
                int posi = __popcll(bal & ((1ull << lane) - 1ull));
                int basei = 0;
                if (lane == leader) basei = atomicAdd(&s_cnt, cnt);
                basei = __shfl(basei, leader, 64);
                if (mt) { int idx = basei + posi; if (idx < SCAP) sbuf[idx] = xs[c]; }
            }
        }
    }
    __syncthreads();
    int n = s_cnt; bool useLds = (n <= SCAP);

    // pass A: bits 18:9 (1024 bins)
    for (int i = tid; i < 1024; i += 256) { hc[i] = 0; hsv[i] = 0.f; }
    __syncthreads();
    if (useLds) {
        for (int i = tid; i < n; i += 256) {
            float x = sbuf[i]; unsigned u = __float_as_uint(x);
            atomicAdd(&hc[(u >> 9) & 1023u], 1); atomicAdd(&hsv[(u >> 9) & 1023u], x);
        }
    } else {
        for (int i = tid; i < PP / 4; i += 256) {
            float4 x = v4[i]; float xs[4] = {x.x, x.y, x.z, x.w};
            for (int c = 0; c < 4; ++c) {
                unsigned u = __float_as_uint(xs[c]);
                if ((u >> 19) == bin1) {
                    atomicAdd(&hc[(u >> 9) & 1023u], 1);
                    atomicAdd(&hsv[(u >> 9) & 1023u], xs[c]);
                }
            }
        }
    }
    __syncthreads();
    suffix_select(1024, hc, hsv, sc, sf, &s_chunk, &s_r, &s_S, &s_bin, tid);
    unsigned bin2 = s_bin;
    unsigned pre2 = (bin1 << 10) | bin2;

    // pass B: bits 8:0 (512 bins)
    for (int i = tid; i < 512; i += 256) { hc[i] = 0; hsv[i] = 0.f; }
    __syncthreads();
    if (useLds) {
        for (int i = tid; i < n; i += 256) {
            float x = sbuf[i]; unsigned u = __float_as_uint(x);
            if (((u >> 9) & 1023u) == bin2) { atomicAdd(&hc[u & 511u], 1); atomicAdd(&hsv[u & 511u], x); }
        }
    } else {
        for (int i = tid; i < PP / 4; i += 256) {
            float4 x = v4[i]; float xs[4] = {x.x, x.y, x.z, x.w};
            for (int c = 0; c < 4; ++c) {
                unsigned u = __float_as_uint(xs[c]);
                if ((u >> 9) == pre2) { atomicAdd(&hc[u & 511u], 1); atomicAdd(&hsv[u & 511u], xs[c]); }
            }
        }
    }
    __syncthreads();
    suffix_select(512, hc, hsv, sc, sf, &s_chunk, &s_r, &s_S, &s_bin, tid);
    if (tid == 0) {
        unsigned tb = (pre2 << 9) | s_bin;
        topk[b] = s_S + (float)s_r * __uint_as_float(tb);
    }
}

// ---- K5: final reduction across batches -> (loss_l/N, loss_c/N) ----
__global__ void k_final(const float* __restrict__ pll, const float* __restrict__ pplc,
                        const int* __restrict__ pnp, const float* __restrict__ topk,
                        float* __restrict__ out) {
    int b = threadIdx.x;          // 64 threads = one wave, one batch each
    float ll = 0.f, plc = 0.f; int np = 0;
    for (int s = 0; s < SS; ++s) {
        ll += pll[s * BB + b];
        plc += pplc[s * BB + b];
        np += pnp[s * BB + b];
    }
    float cc = plc + topk[b];
    for (int s = 32; s > 0; s >>= 1) {
        ll += __shfl_down(ll, s);
        cc += __shfl_down(cc, s);
        np += __shfl_down(np, s);
    }
    if (b == 0) {
        float N = (float)np;
        out[0] = ll / N;
        out[1] = cc / N;
    }
}

extern "C" void kernel_launch(void* const* d_in, const int* in_sizes, int n_in,
                              void* d_out, int out_size, void* d_ws, size_t ws_size,
                              hipStream_t stream) {
    const float* arm_loc  = (const float*)d_in[0];
    const float* arm_conf = (const float*)d_in[1];
    const float* priors   = (const float*)d_in[4];
    const float* targets  = (const float*)d_in[5];
    float* out = (float*)d_out;

    char* w = (char*)d_ws;
    float* bto = (float*)w;  w += sizeof(float) * (size_t)BB * PP;    // 8 MB
    int*   bti = (int*)w;    w += sizeof(int)   * (size_t)BB * PP;    // 8 MB
    float* lcm = (float*)w;  w += sizeof(float) * (size_t)BB * PP;    // 8 MB
    // ---- zeroed region (atomically accumulated) ----
    char* zbase = w;
    u64*   bpm = (u64*)w;    w += sizeof(u64)   * BB * OO;
    int*   Hc  = (int*)w;    w += sizeof(int)   * BB * NBH;           // 1 MB
    float* Hs  = (float*)w;  w += sizeof(float) * BB * NBH;           // 1 MB
    size_t zbytes = (size_t)(w - zbase);
    // ---- plain written-before-read region ----
    float* pll  = (float*)w; w += sizeof(float) * BB * SS;
    float* pplc = (float*)w; w += sizeof(float) * BB * SS;
    int*   pnp  = (int*)w;   w += sizeof(int)   * BB * SS;
    float* topk = (float*)w; w += sizeof(float) * BB;

    int n4 = (int)(zbytes / 16);
    k_zero<<<(n4 + 255) / 256, 256, 0, stream>>>((float4*)zbase, n4);
    k_match<<<dim3(PP / (256 * T1), BB), 256, 0, stream>>>(priors, targets, bto, bti, bpm);
    k_force<<<BB, 64, 0, stream>>>(bpm, bto, bti);
    k_loss<<<dim3(SS, BB), 256, 0, stream>>>(arm_loc, arm_conf, priors, targets,
                                             bto, bti, lcm, pll, pplc, pnp);
    k_hist<<<dim3(8, BB), 256, 0, stream>>>(lcm, Hc, Hs);
    k_resolve<<<BB, 256, 0, stream>>>(lcm, pnp, Hc, Hs, topk);
    k_final<<<1, 64, 0, stream>>>(pll, pplc, pnp, topk, out);
}